// Round 8
// baseline (205.032 us; speedup 1.0000x reference)
//
#include <hip/hip_runtime.h>

// MRConv1d ABLATION ROUND (R11). Output identical to reference on every
// launch; five mrconv variants run back-to-back, each doubling one phase
// idempotently so its marginal cost shows in per-dispatch rocprof dur_us:
//   V0 = baseline (deployed R4 structure, ~43.5 us known)
//   V1 = gather-consume VALU x2 (asm-opaque regs)
//   V3 = MFMA phase x2 (incl. sfeat ds_reads + 64KB/block Wb L2 stream)
//   V4 = edge staging + barrier x2
//   V5 = out stores x2
// Known from R7: gather loads+consume x2 = +11 us. dur_us inflates by design.

#define Bn 4
#define Nn 10000
#define Cn 128
#define Kn 16
#define OUTn 128
#define Mn 16
#define FPAD 8

typedef __attribute__((ext_vector_type(8))) short short8;
typedef __attribute__((ext_vector_type(4))) float floatx4;

__device__ __forceinline__ unsigned short f2bf(float f) {
    union { float f; unsigned u; } v; v.f = f;
    unsigned r = v.u + 0x7fffu + ((v.u >> 16) & 1u);   // RNE
    return (unsigned short)(r >> 16);
}
__device__ __forceinline__ float bf2f(unsigned short h) {
    union { unsigned u; float f; } v; v.u = ((unsigned)h) << 16;
    return v.f;
}

// Fused prep: blocks 0..15 pack W, blocks 16..2515 convert x (8 floats/thread).
__global__ __launch_bounds__(256) void prep_kernel(const float* __restrict__ x,
                                                   const float* __restrict__ W,
                                                   unsigned short* __restrict__ xh,
                                                   unsigned short* __restrict__ Wb) {
    int bi = blockIdx.x;
    int t = threadIdx.x;
    if (bi < 16) {
        int tid = bi * 256 + t;
        int lane = tid & 63;
        int step = (tid >> 6) & 7;
        int tile = tid >> 9;
        int o = tile * 16 + (lane & 15);
        int quad = lane >> 4;
        unsigned short v[8];
#pragma unroll
        for (int j = 0; j < 8; ++j) {
            int c2 = step * 32 + quad * 8 + j;
            v[j] = f2bf(W[o * (2 * Cn) + c2]);
        }
        uint4 pk;
        pk.x = (unsigned)v[0] | ((unsigned)v[1] << 16);
        pk.y = (unsigned)v[2] | ((unsigned)v[3] << 16);
        pk.z = (unsigned)v[4] | ((unsigned)v[5] << 16);
        pk.w = (unsigned)v[6] | ((unsigned)v[7] << 16);
        *(uint4*)(Wb + (size_t)tid * 8) = pk;
        return;
    }
    int i = (bi - 16) * 256 + t;
    const float4* x4 = (const float4*)x;
    float4 a = x4[2 * i];
    float4 c = x4[2 * i + 1];
    uint4 pk;
    pk.x = (unsigned)f2bf(a.x) | ((unsigned)f2bf(a.y) << 16);
    pk.y = (unsigned)f2bf(a.z) | ((unsigned)f2bf(a.w) << 16);
    pk.z = (unsigned)f2bf(c.x) | ((unsigned)f2bf(c.y) << 16);
    pk.w = (unsigned)f2bf(c.z) | ((unsigned)f2bf(c.w) << 16);
    *(uint4*)(xh + 8 * (size_t)i) = pk;
}

template <int V>
__global__ __launch_bounds__(256) void mrconv_kernel(
    const unsigned short* __restrict__ xh, const int* __restrict__ edge,
    const unsigned short* __restrict__ Wb, const float* __restrict__ bias,
    float* __restrict__ out, int z0)   // z0 == 0 at runtime; defeats CSE
{
    __shared__ unsigned short sfeat[Mn][2 * Cn + FPAD];
    __shared__ int sidx[2][Mn][Kn];

    int bi = blockIdx.x;
    int slot = bi & 7;
    int b = slot & 3;
    int nb = (bi >> 3) * 2 + (slot >> 2);
    if (nb >= Nn / Mn) return;
    const int n0 = nb * Mn;
    const int gbase = b * Nn + n0;

    const int t = threadIdx.x;
    const int wv = t >> 6;
    const int lane = t & 63;

    // ---- edge staging ----
    for (int i = t; i < 2 * Mn * Kn; i += 256) {
        int s = i >> 8;
        int m = (i >> 4) & 15;
        int k = i & 15;
        sidx[s][m][k] = __builtin_nontemporal_load(
            &edge[s * (Bn * Nn * Kn) + (gbase + m) * Kn + k]);
    }
    __syncthreads();
    if (V == 4) {  // V4: restage (same values) + extra barrier
        for (int i = t; i < 2 * Mn * Kn; i += 256) {
            int s = i >> 8;
            int m = (i >> 4) & 15;
            int k = i & 15;
            sidx[s][m][k] = __builtin_nontemporal_load(
                &edge[z0 + s * (Bn * Nn * Kn) + (gbase + m) * Kn + k]);
        }
        __syncthreads();
    }

    const unsigned short* xbb = xh + (size_t)b * Nn * Cn;

    // ---- phase 1: gather + max-relative ----
    {
        const int q = lane >> 4;
        const int l16 = lane & 15;
        const int m = wv * 4 + q;
        const int ch = l16 * 8;
        const short8 xs = *(const short8*)(xbb + (n0 + m) * Cn + ch);
        float r[8];
#pragma unroll
        for (int e = 0; e < 8; ++e) r[e] = -3.402823466e+38f;
#pragma unroll
        for (int kc = 0; kc < 2; ++kc) {
            short8 vj[8], vi[8];
#pragma unroll
            for (int u = 0; u < 8; ++u) {
                const int jj = sidx[0][m][kc * 8 + u];
                const int ii = sidx[1][m][kc * 8 + u];
                vj[u] = *(const short8*)(xbb + jj * Cn + ch);
                vi[u] = *(const short8*)(xbb + ii * Cn + ch);
            }
#pragma unroll
            for (int u = 0; u < 8; ++u) {
#pragma unroll
                for (int e = 0; e < 8; ++e) {
                    r[e] = fmaxf(r[e], bf2f((unsigned short)vj[u][e]) -
                                       bf2f((unsigned short)vi[u][e]));
                }
            }
            if (V == 1) {  // V1: consume x2 (idempotent max; opaque regs)
#pragma unroll
                for (int u = 0; u < 8; ++u)
                    asm volatile("" : "+v"(vj[u]), "+v"(vi[u]));
#pragma unroll
                for (int e = 0; e < 8; ++e)
                    asm volatile("" : "+v"(r[e]));
#pragma unroll
                for (int u = 0; u < 8; ++u) {
#pragma unroll
                    for (int e = 0; e < 8; ++e) {
                        r[e] = fmaxf(r[e], bf2f((unsigned short)vj[u][e]) -
                                           bf2f((unsigned short)vi[u][e]));
                    }
                }
            }
        }
        uint4 pk0, pk1;
        pk0.x = (unsigned short)xs[0] | ((unsigned)f2bf(r[0]) << 16);
        pk0.y = (unsigned short)xs[1] | ((unsigned)f2bf(r[1]) << 16);
        pk0.z = (unsigned short)xs[2] | ((unsigned)f2bf(r[2]) << 16);
        pk0.w = (unsigned short)xs[3] | ((unsigned)f2bf(r[3]) << 16);
        pk1.x = (unsigned short)xs[4] | ((unsigned)f2bf(r[4]) << 16);
        pk1.y = (unsigned short)xs[5] | ((unsigned)f2bf(r[5]) << 16);
        pk1.z = (unsigned short)xs[6] | ((unsigned)f2bf(r[6]) << 16);
        pk1.w = (unsigned short)xs[7] | ((unsigned)f2bf(r[7]) << 16);
        *(uint4*)&sfeat[m][2 * ch] = pk0;
        *(uint4*)&sfeat[m][2 * ch + 8] = pk1;
    }
    __syncthreads();

    // ---- phase 2: MFMA ----
    const int m16 = lane & 15;
    const int quad = lane >> 4;
    const short8* wb8 = (const short8*)Wb;
    const int tile0 = 2 * wv, tile1 = 2 * wv + 1;

    if (V == 3) {  // V3: dummy MFMA pass first (kept live), then real pass
        floatx4 da0 = {0.f, 0.f, 0.f, 0.f};
        floatx4 da1 = {0.f, 0.f, 0.f, 0.f};
#pragma unroll
        for (int step = 0; step < 8; ++step) {
            short8 a = *(const short8*)&sfeat[m16][step * 32 + quad * 8];
            short8 b0 = wb8[z0 + (tile0 * 8 + step) * 64 + lane];
            short8 b1 = wb8[z0 + (tile1 * 8 + step) * 64 + lane];
            da0 = __builtin_amdgcn_mfma_f32_16x16x32_bf16(a, b0, da0, 0, 0, 0);
            da1 = __builtin_amdgcn_mfma_f32_16x16x32_bf16(a, b1, da1, 0, 0, 0);
        }
        asm volatile("" :: "v"(da0), "v"(da1) : "memory");
    }

    floatx4 acc0 = {0.f, 0.f, 0.f, 0.f};
    floatx4 acc1 = {0.f, 0.f, 0.f, 0.f};
#pragma unroll
    for (int step = 0; step < 8; ++step) {
        short8 a = *(const short8*)&sfeat[m16][step * 32 + quad * 8];
        short8 b0 = wb8[(tile0 * 8 + step) * 64 + lane];
        short8 b1 = wb8[(tile1 * 8 + step) * 64 + lane];
        acc0 = __builtin_amdgcn_mfma_f32_16x16x32_bf16(a, b0, acc0, 0, 0, 0);
        acc1 = __builtin_amdgcn_mfma_f32_16x16x32_bf16(a, b1, acc1, 0, 0, 0);
    }

    const int o0 = tile0 * 16 + m16;
    const int o1 = tile1 * 16 + m16;
    const float bb0 = bias[o0], bb1 = bias[o1];
#pragma unroll
    for (int r = 0; r < 4; ++r) {
        int g = gbase + quad * 4 + r;
        __builtin_nontemporal_store(fmaxf(acc0[r] + bb0, 0.f), &out[g * OUTn + o0]);
        __builtin_nontemporal_store(fmaxf(acc1[r] + bb1, 0.f), &out[g * OUTn + o1]);
    }
    if (V == 5) {  // V5: store again (same values, opaque address base)
#pragma unroll
        for (int r = 0; r < 4; ++r) {
            int g = gbase + quad * 4 + r;
            __builtin_nontemporal_store(fmaxf(acc0[r] + bb0, 0.f), &out[z0 + g * OUTn + o0]);
            __builtin_nontemporal_store(fmaxf(acc1[r] + bb1, 0.f), &out[z0 + g * OUTn + o1]);
        }
    }
}

extern "C" void kernel_launch(void* const* d_in, const int* in_sizes, int n_in,
                              void* d_out, int out_size, void* d_ws, size_t ws_size,
                              hipStream_t stream) {
    const float* x = (const float*)d_in[0];
    const int* edge = (const int*)d_in[1];
    const float* W = (const float*)d_in[2];
    const float* bias = (const float*)d_in[3];
    float* out = (float*)d_out;

    unsigned short* Wb = (unsigned short*)d_ws;                  // 64 KB
    unsigned short* xh = (unsigned short*)((char*)d_ws + 65536); // 10.24 MB

    prep_kernel<<<2516, 256, 0, stream>>>(x, W, xh, Wb);
    // Ablation matrix: every launch writes the identical correct output.
    mrconv_kernel<0><<<2560, 256, 0, stream>>>(xh, edge, Wb, bias, out, 0);
    mrconv_kernel<1><<<2560, 256, 0, stream>>>(xh, edge, Wb, bias, out, 0);
    mrconv_kernel<3><<<2560, 256, 0, stream>>>(xh, edge, Wb, bias, out, 0);
    mrconv_kernel<4><<<2560, 256, 0, stream>>>(xh, edge, Wb, bias, out, 0);
    mrconv_kernel<5><<<2560, 256, 0, stream>>>(xh, edge, Wb, bias, out, 0);
}

// Round 10
// 103.789 us; speedup vs baseline: 1.9755x; 1.9755x over previous
//
#include <hip/hip_runtime.h>

// MRConv1d: B=4, N=10000, C=128, K=16, OUT=128
// out[b,n,o] = relu( sum_c2 feat[b,n,c2]*W[o,c2] + bias[o] )
// feat[b,n,2c]   = x[b,n,c]
// feat[b,n,2c+1] = max_k( x[b, e0[b,n,k], c] - x[b, e1[b,n,k], c] )
//
// Ledger: R4 nt-hints null. R6 batch/launch regressed. R8 cross-kernel L2
//   pre-warm null. R9 XCD atomic queue regressed; counters: FETCH=compulsory,
//   all pipes idle => latency-bound, not BW/capacity. R10 MLP/VGPR null.
//   R11 ablation: no single phase dominates; warm-repeat runs ~20 us vs 43
//   solo => ~23 us is COLD-CACHE latency premium on the one real pass.
//   R12 cooperative warm+grid.sync: FAILED -- hipLaunchCooperativeKernel
//   silently no-ops under graph capture (out never written). Don't use it.
// R13 (this round): in-kernel warm prefix, no sync needed (warming is a pure
//   prefetch; races are harmless). With the bid&7 swizzle, XCD s serves batch
//   s&3. Ranks 0..159 of each XCD (first ~2 generations) linearly stream one
//   16 KB chunk each => full 2.56 MB slice lands in the local L2 in ~4 us,
//   overlapped with edge-staging latency. Gen 2+ gathers (~80% of blocks)
//   then hit warm local L2. Rest of the kernel = proven R4 102.0 us config.

#define Bn 4
#define Nn 10000
#define Cn 128
#define Kn 16
#define OUTn 128
#define Mn 16           // nodes per block
#define FPAD 8          // sfeat row pad (row = 264 ushorts = 528 B)

typedef __attribute__((ext_vector_type(8))) short short8;
typedef __attribute__((ext_vector_type(4))) float floatx4;

__device__ __forceinline__ unsigned short f2bf(float f) {
    union { float f; unsigned u; } v; v.f = f;
    unsigned r = v.u + 0x7fffu + ((v.u >> 16) & 1u);   // RNE
    return (unsigned short)(r >> 16);
}
__device__ __forceinline__ float bf2f(unsigned short h) {
    union { unsigned u; float f; } v; v.u = ((unsigned)h) << 16;
    return v.f;
}

// Fused prep: blocks 0..15 pack W, blocks 16..2515 convert x (8 floats/thread).
__global__ __launch_bounds__(256) void prep_kernel(const float* __restrict__ x,
                                                   const float* __restrict__ W,
                                                   unsigned short* __restrict__ xh,
                                                   unsigned short* __restrict__ Wb) {
    int bi = blockIdx.x;
    int t = threadIdx.x;
    if (bi < 16) {
        int tid = bi * 256 + t;                 // 0..4095
        int lane = tid & 63;
        int step = (tid >> 6) & 7;
        int tile = tid >> 9;
        int o = tile * 16 + (lane & 15);
        int quad = lane >> 4;
        unsigned short v[8];
#pragma unroll
        for (int j = 0; j < 8; ++j) {
            int c2 = step * 32 + quad * 8 + j;
            v[j] = f2bf(W[o * (2 * Cn) + c2]);
        }
        uint4 pk;
        pk.x = (unsigned)v[0] | ((unsigned)v[1] << 16);
        pk.y = (unsigned)v[2] | ((unsigned)v[3] << 16);
        pk.z = (unsigned)v[4] | ((unsigned)v[5] << 16);
        pk.w = (unsigned)v[6] | ((unsigned)v[7] << 16);
        *(uint4*)(Wb + (size_t)tid * 8) = pk;
        return;
    }
    int i = (bi - 16) * 256 + t;                // 0..639999
    const float4* x4 = (const float4*)x;
    float4 a = x4[2 * i];
    float4 c = x4[2 * i + 1];
    uint4 pk;
    pk.x = (unsigned)f2bf(a.x) | ((unsigned)f2bf(a.y) << 16);
    pk.y = (unsigned)f2bf(a.z) | ((unsigned)f2bf(a.w) << 16);
    pk.z = (unsigned)f2bf(c.x) | ((unsigned)f2bf(c.y) << 16);
    pk.w = (unsigned)f2bf(c.z) | ((unsigned)f2bf(c.w) << 16);
    *(uint4*)(xh + 8 * (size_t)i) = pk;
}

__global__ __launch_bounds__(256) void mrconv_kernel(
    const unsigned short* __restrict__ xh, const int* __restrict__ edge,
    const unsigned short* __restrict__ Wb, const float* __restrict__ bias,
    float* __restrict__ out)
{
    __shared__ unsigned short sfeat[Mn][2 * Cn + FPAD];  // bf16 feature tile
    __shared__ int sidx[2][Mn][Kn];

    // XCD mapping: batch b on XCD slots {b, b+4} (bid%8 -> XCD round-robin).
    int bi = blockIdx.x;
    int slot = bi & 7;
    int b = slot & 3;
    int nb = (bi >> 3) * 2 + (slot >> 2);
    if (nb >= Nn / Mn) return;
    const int n0 = nb * Mn;
    const int gbase = b * Nn + n0;

    const int t = threadIdx.x;
    const int wv = t >> 6;      // wave 0..3
    const int lane = t & 63;

    // ---- warm prefix: ranks 0..159 of each XCD stream the XCD's batch slice
    // into the LOCAL L2 (linear, latency-tolerant; 160 x 1000 uint4 = 2.56 MB
    // exactly). Pure prefetch -- no sync needed; issued before edge staging so
    // it overlaps the staging latency. Results consumed after phase 1.
    unsigned wx = 0, wy = 0, wz = 0, ww = 0;
    {
        const int r = bi >> 3;            // rank within this XCD: 0..319
        if (r < 160) {
            const uint4* slice = (const uint4*)(xh + (size_t)b * Nn * Cn);
#pragma unroll
            for (int it = 0; it < 4; ++it) {
                int o = it * 250 + t;
                if (o < 1000) {
                    uint4 v = slice[(size_t)r * 1000 + o];
                    wx ^= v.x; wy ^= v.y; wz ^= v.z; ww ^= v.w;
                }
            }
        }
    }

    // stage edge indices for the block's 16 nodes: 2*16*16 = 512 ints.
    for (int i = t; i < 2 * Mn * Kn; i += 256) {
        int s = i >> 8;
        int m = (i >> 4) & 15;
        int k = i & 15;
        sidx[s][m][k] = __builtin_nontemporal_load(
            &edge[s * (Bn * Nn * Kn) + (gbase + m) * Kn + k]);
    }
    __syncthreads();

    const unsigned short* xbb = xh + (size_t)b * Nn * Cn;

    // phase 1: gather + max-relative in bf16 (proven R4 body).
    {
        const int q = lane >> 4;          // quarter 0..3
        const int l16 = lane & 15;
        const int m = wv * 4 + q;         // node 0..15
        const int ch = l16 * 8;           // 8 channels per lane
        const short8 xs = *(const short8*)(xbb + (n0 + m) * Cn + ch);
        float r[8];
#pragma unroll
        for (int e = 0; e < 8; ++e) r[e] = -3.402823466e+38f;
#pragma unroll
        for (int kc = 0; kc < 2; ++kc) {
            short8 vj[8], vi[8];
#pragma unroll
            for (int u = 0; u < 8; ++u) {
                const int jj = sidx[0][m][kc * 8 + u];
                const int ii = sidx[1][m][kc * 8 + u];
                vj[u] = *(const short8*)(xbb + jj * Cn + ch);
                vi[u] = *(const short8*)(xbb + ii * Cn + ch);
            }
#pragma unroll
            for (int u = 0; u < 8; ++u) {
#pragma unroll
                for (int e = 0; e < 8; ++e) {
                    r[e] = fmaxf(r[e], bf2f((unsigned short)vj[u][e]) -
                                       bf2f((unsigned short)vi[u][e]));
                }
            }
        }
        // interleaved bf16 row: {x_c, rel_c} pairs; lane covers c in [ch, ch+8)
        uint4 pk0, pk1;
        pk0.x = (unsigned short)xs[0] | ((unsigned)f2bf(r[0]) << 16);
        pk0.y = (unsigned short)xs[1] | ((unsigned)f2bf(r[1]) << 16);
        pk0.z = (unsigned short)xs[2] | ((unsigned)f2bf(r[2]) << 16);
        pk0.w = (unsigned short)xs[3] | ((unsigned)f2bf(r[3]) << 16);
        pk1.x = (unsigned short)xs[4] | ((unsigned)f2bf(r[4]) << 16);
        pk1.y = (unsigned short)xs[5] | ((unsigned)f2bf(r[5]) << 16);
        pk1.z = (unsigned short)xs[6] | ((unsigned)f2bf(r[6]) << 16);
        pk1.w = (unsigned short)xs[7] | ((unsigned)f2bf(r[7]) << 16);
        *(uint4*)&sfeat[m][2 * ch] = pk0;
        *(uint4*)&sfeat[m][2 * ch + 8] = pk1;
    }
    __syncthreads();

    // consume warm loads (keeps them live; rule #17). After the barrier so the
    // implied s_waitcnt doesn't delay the gather issue.
    asm volatile("" :: "v"(wx), "v"(wy), "v"(wz), "v"(ww));

    // phase 2: out_tile[16 nodes][128] = feat[16][256] @ Wt[256][128] via MFMA.
    const int m16 = lane & 15;
    const int quad = lane >> 4;
    floatx4 acc0 = {0.f, 0.f, 0.f, 0.f};
    floatx4 acc1 = {0.f, 0.f, 0.f, 0.f};
    const short8* wb8 = (const short8*)Wb;
    const int tile0 = 2 * wv, tile1 = 2 * wv + 1;
#pragma unroll
    for (int step = 0; step < 8; ++step) {
        short8 a = *(const short8*)&sfeat[m16][step * 32 + quad * 8];
        short8 b0 = wb8[(tile0 * 8 + step) * 64 + lane];
        short8 b1 = wb8[(tile1 * 8 + step) * 64 + lane];
        acc0 = __builtin_amdgcn_mfma_f32_16x16x32_bf16(a, b0, acc0, 0, 0, 0);
        acc1 = __builtin_amdgcn_mfma_f32_16x16x32_bf16(a, b1, acc1, 0, 0, 0);
    }
    // C/D layout: col = lane&15, row = quad*4 + reg
    const int o0 = tile0 * 16 + m16;
    const int o1 = tile1 * 16 + m16;
    const float bb0 = bias[o0], bb1 = bias[o1];
#pragma unroll
    for (int r = 0; r < 4; ++r) {
        int g = gbase + quad * 4 + r;
        __builtin_nontemporal_store(fmaxf(acc0[r] + bb0, 0.f), &out[g * OUTn + o0]);
        __builtin_nontemporal_store(fmaxf(acc1[r] + bb1, 0.f), &out[g * OUTn + o1]);
    }
}

extern "C" void kernel_launch(void* const* d_in, const int* in_sizes, int n_in,
                              void* d_out, int out_size, void* d_ws, size_t ws_size,
                              hipStream_t stream) {
    const float* x = (const float*)d_in[0];
    const int* edge = (const int*)d_in[1];
    const float* W = (const float*)d_in[2];
    const float* bias = (const float*)d_in[3];
    float* out = (float*)d_out;

    unsigned short* Wb = (unsigned short*)d_ws;                  // 64 KB
    unsigned short* xh = (unsigned short*)((char*)d_ws + 65536); // 10.24 MB

    prep_kernel<<<2516, 256, 0, stream>>>(x, W, xh, Wb);
    mrconv_kernel<<<2560, 256, 0, stream>>>(xh, edge, Wb, bias, out);
}